// Round 9
// baseline (73.906 us; speedup 1.0000x reference)
//
#include <hip/hip_runtime.h>

#define DM     1024
#define NTOK   32768   // B*S
#define NRED   16384
#define NSAVE  16384
#define MMAX   16384   // max compacted rows
#define SPLITK 2
#define KWIN   (DM / SPLITK)   // 512 -> 8 steps of BK=64

typedef __attribute__((ext_vector_type(8)))  short bf16x8;
typedef __attribute__((ext_vector_type(4)))  float f32x4;
typedef __attribute__((ext_vector_type(16))) float f32x16;

__device__ __forceinline__ ushort f2bf(float f) {
    union { float f; unsigned u; } v; v.f = f;
    unsigned r = (v.u + 0x7FFF + ((v.u >> 16) & 1)) >> 16;   // RNE
    return (ushort)r;
}
__device__ __forceinline__ float bf2f(ushort u) {
    union { unsigned u; float f; } v; v.u = ((unsigned)u) << 16;
    return v.f;
}

// ---------------------------------------------------------------------------
__global__ __launch_bounds__(256) void setup_kernel(const float* __restrict__ W,
                                                    ushort* __restrict__ Wb,
                                                    int* __restrict__ cnt,
                                                    int* __restrict__ need,
                                                    int* __restrict__ counter) {
    int t = blockIdx.x * 256 + threadIdx.x;
    float4 v = ((const float4*)W)[t];
    ushort4 o;
    o.x = f2bf(v.x); o.y = f2bf(v.y); o.z = f2bf(v.z); o.w = f2bf(v.w);
    ((ushort4*)Wb)[t] = o;
    if (t < NTOK) { cnt[t] = 0; need[t] = 0; }
    if (t == 0) *counter = 0;
}

// ---------------------------------------------------------------------------
__global__ __launch_bounds__(256) void prep_kernel(const int* __restrict__ red,
                                                   const int* __restrict__ sav,
                                                   int* __restrict__ cnt,
                                                   int* __restrict__ need) {
    int j = blockIdx.x * 256 + threadIdx.x;
    if (j >= NRED) return;
    atomicAdd(&cnt[red[j]], 1);
    int s = sav[j];
    if (s > 0) need[s - 1] = 1;
}

// ---------------------------------------------------------------------------
__global__ __launch_bounds__(256) void compact_kernel(const int* __restrict__ cnt,
                                                      const int* __restrict__ need,
                                                      int* __restrict__ inv,
                                                      int* __restrict__ list,
                                                      int* __restrict__ counter) {
    int t = blockIdx.x * 256 + threadIdx.x;
    if (t >= NTOK) return;
    if (need[t] && cnt[t] > 0) {
        int pos = atomicAdd(counter, 1);
        inv[t] = pos;
        list[pos] = t;
    }
}

// ---------------------------------------------------------------------------
// convx: gather + fp32->bf16 convert compacted rows; zero-pad to 128 multiple
// ---------------------------------------------------------------------------
__global__ __launch_bounds__(256) void convx_kernel(const float* __restrict__ X,
                                                    const int* __restrict__ list,
                                                    const int* __restrict__ counter,
                                                    ushort* __restrict__ Xb) {
    const int M = *counter;
    const int Mpad = (M + 127) & ~127;
    for (int r = blockIdx.x; r < Mpad; r += gridDim.x) {
        ushort4 o;
        if (r < M) {
            int src = list[r];
            float4 v = ((const float4*)(X + (size_t)src * DM))[threadIdx.x];
            o.x = f2bf(v.x); o.y = f2bf(v.y); o.z = f2bf(v.z); o.w = f2bf(v.w);
        } else {
            o.x = 0; o.y = 0; o.z = 0; o.w = 0;
        }
        ((ushort4*)(Xb + (size_t)r * DM))[threadIdx.x] = o;
    }
}

// ---------------------------------------------------------------------------
// Split-K bf16 MFMA GEMM via 32x32x16: Tp[z][m,n] = bf16( sum_{k in win z} )
// BM=BN=128, BK=64, 4 waves, blockIdx.z = K-window (512 each, 8 steps).
// Wave (wm,wn) owns a 64x64 sub-tile = 2x2 frags of 32x32 (acc 64 VGPR).
// Per wave-step: 8 staging gload_lds + 16 b128 reads + 16 MFMA(32k FLOP).
// Rationale (r8 post-mortem): occupancy, not LDS pipe, limits this shape;
// split-K doubles wgs to 640 (=2560 waves, ~10/CU, 2 wg/CU LDS-resident)
// and cuts the serial K-chain per wg in half, while 32x32 frags keep the
// LDS pipe at ~1 b128/MFMA. Counted vmcnt(8) + raw s_barrier (T4); staging
// source pre-swizzled chunk^=row&7 (rule #21) -> conflict-free ds_read_b128.
// ---------------------------------------------------------------------------
__global__ __launch_bounds__(256) void gemm_kernel(const ushort* __restrict__ Xb,
                                                   const ushort* __restrict__ Wb,
                                                   const int* __restrict__ counter,
                                                   ushort* __restrict__ Tp) {
    const int M = *counter;
    const int m0 = blockIdx.x * 128;
    if (m0 >= M) return;                 // uniform exit before any barrier
    const int n0 = blockIdx.y * 128;
    const int kbase = blockIdx.z * KWIN;
    ushort* Tout = Tp + (size_t)blockIdx.z * MMAX * DM;

    __shared__ char lds[65536];          // 2 bufs x (A 16KB + B 16KB)

    const int tid = threadIdx.x;
    const int l   = tid & 63;
    const int w   = tid >> 6;            // 0..3

    // ---- staging: wave w covers rows [w*32, w*32+32) of both A and B;
    // instr i covers 8 rows; lane: row = w*32 + i*8 + (l>>3), stored slot l&7,
    // logical chunk = (l&7)^(row&7); row&7 == (l>>3)&7 independent of i,w.
    const int srow   = l >> 3;
    const int schunk = (l & 7) ^ (srow & 7);
    const ushort* aS = Xb + (size_t)(m0 + w * 32 + srow) * DM + kbase + schunk * 8;
    const ushort* bS = Wb + (size_t)(n0 + w * 32 + srow) * DM + kbase + schunk * 8;
    const int dOff = w * 4096;           // byte offset of wave's 32-row band

#define STAGE(buf, k0) do {                                                          \
    char* _a = lds + (buf) * 32768 + dOff;                                           \
    _Pragma("unroll")                                                                \
    for (int _i = 0; _i < 4; ++_i) {                                                 \
        __builtin_amdgcn_global_load_lds(                                            \
            (const __attribute__((address_space(1))) unsigned*)(aS + (k0) + _i * 8 * DM), \
            (__attribute__((address_space(3))) unsigned*)(_a + _i * 1024), 16, 0, 0);      \
        __builtin_amdgcn_global_load_lds(                                            \
            (const __attribute__((address_space(1))) unsigned*)(bS + (k0) + _i * 8 * DM), \
            (__attribute__((address_space(3))) unsigned*)(_a + 16384 + _i * 1024), 16, 0, 0); \
    }                                                                                \
} while (0)

    // ---- fragment read bases; chunk(ks) = ((ks*2 + h) ^ e) * 16
    const int wm  = w >> 1, wn = w & 1;
    const int h   = l >> 5;              // k-half selector
    const int e   = l & 7;
    const int r32 = l & 31;
    int arow[2], brow[2];
#pragma unroll
    for (int fm = 0; fm < 2; ++fm) arow[fm] = (wm * 64 + fm * 32 + r32) * 128;
#pragma unroll
    for (int fn = 0; fn < 2; ++fn) brow[fn] = 16384 + (wn * 64 + fn * 32 + r32) * 128;

    f32x16 acc[2][2] = {};

    STAGE(0, 0);
#pragma unroll
    for (int t = 0; t < 8; ++t) {
        const char* base = lds + (t & 1) * 32768;
        if (t < 7) {
            STAGE((t & 1) ^ 1, (t + 1) * 64);
            asm volatile("s_waitcnt vmcnt(8)" ::: "memory");   // my cur-buf 8 loads landed
        } else {
            asm volatile("s_waitcnt vmcnt(0)" ::: "memory");
        }
        __builtin_amdgcn_sched_barrier(0);
        __builtin_amdgcn_s_barrier();                          // everyone's cur loads landed

#pragma unroll
        for (int ks = 0; ks < 4; ++ks) {
            const int cs = (((ks * 2 + h) ^ e) << 4);
            bf16x8 af[2], bfr[2];
#pragma unroll
            for (int fm = 0; fm < 2; ++fm) af[fm]  = *(const bf16x8*)(base + arow[fm] + cs);
#pragma unroll
            for (int fn = 0; fn < 2; ++fn) bfr[fn] = *(const bf16x8*)(base + brow[fn] + cs);
#pragma unroll
            for (int fm = 0; fm < 2; ++fm)
#pragma unroll
                for (int fn = 0; fn < 2; ++fn)
                    acc[fm][fn] = __builtin_amdgcn_mfma_f32_32x32x16_bf16(af[fm], bfr[fn], acc[fm][fn], 0, 0, 0);
        }

        if (t < 7)
            __builtin_amdgcn_s_barrier();   // all reads of cur done -> next STAGE may overwrite
    }
#undef STAGE

    // C/D layout (32x32): col = lane&31, row = (reg&3) + 8*(reg>>2) + 4*(lane>>5) [m74/m101]
#pragma unroll
    for (int fm = 0; fm < 2; ++fm) {
        int mband = m0 + wm * 64 + fm * 32;
#pragma unroll
        for (int fn = 0; fn < 2; ++fn) {
            int n = n0 + wn * 64 + fn * 32 + r32;
#pragma unroll
            for (int r = 0; r < 16; ++r) {
                int m = mband + (r & 3) + 8 * (r >> 2) + 4 * h;
                if (m < M) Tout[(size_t)m * DM + n] = f2bf(acc[fm][fn][r]);
            }
        }
    }
}

// ---------------------------------------------------------------------------
// epilogue: out[r] = x[s] + cnt[s-1] * (Tp0[inv[s-1]] + Tp1[inv[s-1]])
// ---------------------------------------------------------------------------
__global__ __launch_bounds__(256) void out_kernel(const float* __restrict__ X,
                                                  const ushort* __restrict__ Tp,
                                                  const int* __restrict__ sav,
                                                  const int* __restrict__ cnt,
                                                  const int* __restrict__ inv,
                                                  float* __restrict__ out) {
    int r = blockIdx.x;
    int d = threadIdx.x;                 // float4 lane, 0..255
    int s = sav[r];
    const float4* xr = (const float4*)(X + (size_t)s * DM);
    float4 v = xr[d];
    if (s > 0) {
        int t = s - 1;
        int c = cnt[t];
        if (c > 0) {
            float fc = (float)c;
            size_t rowoff = (size_t)inv[t] * DM;
            ushort4 p0 = ((const ushort4*)(Tp + rowoff))[d];
            ushort4 p1 = ((const ushort4*)(Tp + (size_t)MMAX * DM + rowoff))[d];
            v.x += fc * (bf2f(p0.x) + bf2f(p1.x));
            v.y += fc * (bf2f(p0.y) + bf2f(p1.y));
            v.z += fc * (bf2f(p0.z) + bf2f(p1.z));
            v.w += fc * (bf2f(p0.w) + bf2f(p1.w));
        }
    }
    ((float4*)out)[(size_t)r * (DM / 4) + d] = v;
}

// ---------------------------------------------------------------------------
extern "C" void kernel_launch(void* const* d_in, const int* in_sizes, int n_in,
                              void* d_out, int out_size, void* d_ws, size_t ws_size,
                              hipStream_t stream) {
    const float* X   = (const float*)d_in[0];
    const float* W   = (const float*)d_in[1];
    const int*   sav = (const int*)d_in[2];   // ids_to_save
    const int*   red = (const int*)d_in[3];   // ids_to_reduce
    float* out = (float*)d_out;

    char* ws = (char*)d_ws;
    int* counter = (int*)ws;                  // 64 ints
    int* cnt  = counter + 64;                 // 32768
    int* need = cnt + NTOK;                   // 32768
    int* inv  = need + NTOK;                  // 32768
    int* list = inv + NTOK;                   // 16384  (ends < 512 KB)
    ushort* Wb = (ushort*)(ws + (1 << 19));   // 2 MB bf16 W
    ushort* Xb = (ushort*)(ws + (4 << 20));   // 32 MB bf16 compacted X rows (padded)
    ushort* Tp = (ushort*)(ws + (36u << 20)); // 2 x 32 MB bf16 split-K partials

    setup_kernel<<<DM * DM / 4 / 256, 256, 0, stream>>>(W, Wb, cnt, need, counter);
    prep_kernel<<<NRED / 256, 256, 0, stream>>>(red, sav, cnt, need);
    compact_kernel<<<NTOK / 256, 256, 0, stream>>>(cnt, need, inv, list, counter);
    convx_kernel<<<2048, 256, 0, stream>>>(X, list, counter, Xb);

    dim3 ggrid(MMAX / 128, DM / 128, SPLITK); // x = m-blocks (early-exit), y = n (8), z = K-split
    gemm_kernel<<<ggrid, 256, 0, stream>>>(Xb, Wb, counter, Tp);

    out_kernel<<<NSAVE, 256, 0, stream>>>(X, Tp, sav, cnt, inv, out);
}